// Round 3
// baseline (1566.838 us; speedup 1.0000x reference)
//
#include <hip/hip_runtime.h>
#include <math.h>

#define NQn 100000
#define NKVn 100000
#define NEn 2000000
// D=64, H=4, F=16. CSR scan: chunks of 1024, NB blocks.
#define SCAN_NB ((NQn + 1023) / 1024)

// ---------------- zero-init ------------------------------------------------
__global__ void zero_kernel(int* __restrict__ p, int n) {
    int i = blockIdx.x * blockDim.x + threadIdx.x;
    int stride = gridDim.x * blockDim.x;
    for (; i < n; i += stride) p[i] = 0;
}

// ---------------- CSR build: histogram ------------------------------------
__global__ void hist_kernel(const int* __restrict__ t, int* __restrict__ cnt) {
    int i = blockIdx.x * blockDim.x + threadIdx.x;
    int stride = gridDim.x * blockDim.x;
    for (; i < NEn; i += stride) atomicAdd(&cnt[t[i]], 1);
}

// per-1024-chunk sums
__global__ void scan_bsum_kernel(const int* __restrict__ cnt, int* __restrict__ bsum) {
    __shared__ int ls[256];
    int b = blockIdx.x;
    int base = b * 1024 + threadIdx.x * 4;
    int tot = 0;
    #pragma unroll
    for (int k = 0; k < 4; ++k) {
        int idx = base + k;
        tot += (idx < NQn) ? cnt[idx] : 0;
    }
    ls[threadIdx.x] = tot;
    __syncthreads();
    for (int off = 128; off > 0; off >>= 1) {
        if (threadIdx.x < off) ls[threadIdx.x] += ls[threadIdx.x + off];
        __syncthreads();
    }
    if (threadIdx.x == 0) bsum[b] = ls[0];
}

// exclusive scan of block sums (single block, serial — NB=98)
__global__ void scan_base_kernel(const int* __restrict__ bsum, int* __restrict__ bbase,
                                 int* __restrict__ ptr) {
    if (threadIdx.x == 0 && blockIdx.x == 0) {
        int run = 0;
        for (int b = 0; b < SCAN_NB; ++b) { bbase[b] = run; run += bsum[b]; }
        ptr[NQn] = run;   // == NEn
    }
}

// final: exclusive scan within chunk + base; write ptr and fill (copy)
__global__ void scan_final_kernel(const int* __restrict__ cnt, const int* __restrict__ bbase,
                                  int* __restrict__ ptr, int* __restrict__ fill) {
    __shared__ int ls[256];
    int b = blockIdx.x;
    int base = b * 1024 + threadIdx.x * 4;
    int c[4];
    int tot = 0;
    #pragma unroll
    for (int k = 0; k < 4; ++k) {
        int idx = base + k;
        c[k] = (idx < NQn) ? cnt[idx] : 0;
        tot += c[k];
    }
    ls[threadIdx.x] = tot;
    __syncthreads();
    // Hillis-Steele inclusive scan over 256 thread totals
    for (int off = 1; off < 256; off <<= 1) {
        int v = (threadIdx.x >= off) ? ls[threadIdx.x - off] : 0;
        __syncthreads();
        ls[threadIdx.x] += v;
        __syncthreads();
    }
    int run = ((threadIdx.x > 0) ? ls[threadIdx.x - 1] : 0) + bbase[b];
    #pragma unroll
    for (int k = 0; k < 4; ++k) {
        int idx = base + k;
        if (idx < NQn) { ptr[idx] = run; fill[idx] = run; run += c[k]; }
    }
}

// scatter: sorted_s[slot] = s[e], slot = atomic bump of fill[t[e]]
__global__ void scatter_kernel(const int* __restrict__ t, const int* __restrict__ s,
                               int* __restrict__ fill, int* __restrict__ sorted_s) {
    int i = blockIdx.x * blockDim.x + threadIdx.x;
    int stride = gridDim.x * blockDim.x;
    for (; i < NEn; i += stride) {
        int pos = atomicAdd(&fill[t[i]], 1);
        sorted_s[pos] = s[i];
    }
}

// ---------------- kv projection: kvb[r,0:128] = other[r,:] @ Wkv ----------
__global__ void kvproj_kernel(const float* __restrict__ x, const float* __restrict__ W,
                              float* __restrict__ out) {
    __shared__ float Wl[64 * 128];
    for (int i = threadIdx.x; i < 64 * 128; i += blockDim.x) Wl[i] = W[i];
    __syncthreads();
    const int lane = threadIdx.x & 63;
    const int wid  = blockIdx.x * (blockDim.x >> 6) + (threadIdx.x >> 6);
    const int nw   = gridDim.x * (blockDim.x >> 6);
    for (int r = wid; r < NKVn; r += nw) {
        float xv = x[(size_t)r * 64 + lane];
        float acc0 = 0.f, acc1 = 0.f;
        #pragma unroll
        for (int k = 0; k < 64; ++k) {
            float xk = __shfl(xv, k, 64);
            acc0 += xk * Wl[k * 128 + lane];
            acc1 += xk * Wl[k * 128 + lane + 64];
        }
        out[(size_t)r * 128 + lane]      = acc0;
        out[(size_t)r * 128 + lane + 64] = acc1;
    }
}

// ---------------- fused node kernel ---------------------------------------
// wave per target node: q-proj (in-reg) -> edge loop (no atomics) ->
// normalize -> out-proj -> store. lane l: head l>>4, dim l&15; owns out col l.
__global__ void node_kernel(const float* __restrict__ input, const float* __restrict__ Wq,
                            const int* __restrict__ ptr, const int* __restrict__ sorted_s,
                            const float* __restrict__ kvb,
                            const float* __restrict__ Wo, const float* __restrict__ bo,
                            float* __restrict__ out) {
    __shared__ float WqL[64 * 64];
    __shared__ float WoL[64 * 64];
    for (int i = threadIdx.x; i < 64 * 64; i += blockDim.x) {
        WqL[i] = Wq[i];
        WoL[i] = Wo[i];
    }
    __syncthreads();
    const int lane = threadIdx.x & 63;
    const int wid  = blockIdx.x * (blockDim.x >> 6) + (threadIdx.x >> 6);
    const int nw   = gridDim.x * (blockDim.x >> 6);
    const float b = bo[lane];

    for (int r = wid; r < NQn; r += nw) {
        // --- q projection into registers ---
        float xv = input[(size_t)r * 64 + lane];
        float qv = 0.f;
        #pragma unroll
        for (int k = 0; k < 64; ++k)
            qv += __shfl(xv, k, 64) * WqL[k * 64 + lane];

        // --- edge loop ---
        int beg = ptr[r], end = ptr[r + 1];
        float accl = 0.f, sl = 0.f;
        int si_next = (beg < end) ? sorted_s[beg] : 0;
        for (int e = beg; e < end; ++e) {
            int si = si_next;
            if (e + 1 < end) si_next = sorted_s[e + 1];
            float kk = kvb[(size_t)si * 128 + lane];
            float vv = kvb[(size_t)si * 128 + 64 + lane];
            float p = qv * kk;
            p += __shfl_xor(p, 8, 64);
            p += __shfl_xor(p, 4, 64);
            p += __shfl_xor(p, 2, 64);
            p += __shfl_xor(p, 1, 64);
            float ex = __expf(p * 0.25f);      // /sqrt(F), F=16
            accl += ex * vv;
            sl   += ex;
        }
        float val = (end > beg) ? accl / sl : 0.f;

        // --- output projection + bias ---
        float o = b;
        #pragma unroll
        for (int k = 0; k < 64; ++k)
            o += __shfl(val, k, 64) * WoL[k * 64 + lane];
        out[(size_t)r * 64 + lane] = o;
    }
}

extern "C" void kernel_launch(void* const* d_in, const int* in_sizes, int n_in,
                              void* d_out, int out_size, void* d_ws, size_t ws_size,
                              hipStream_t stream) {
    const float* input = (const float*)d_in[0];
    const float* other = (const float*)d_in[1];
    const int*   t     = (const int*)  d_in[2];
    const int*   s     = (const int*)  d_in[3];
    const float* Wq    = (const float*)d_in[4];
    const float* Wkv   = (const float*)d_in[5];
    const float* Wo    = (const float*)d_in[6];
    const float* bo    = (const float*)d_in[7];
    float* out = (float*)d_out;

    // workspace layout
    char* w = (char*)d_ws;
    float* kvb      = (float*)w;                 w += (size_t)NKVn * 128 * 4;  // 51.2 MB
    int*   cnt      = (int*)w;                   w += (size_t)NQn * 4;
    int*   ptr      = (int*)w;                   w += ((size_t)NQn + 1) * 4;
    int*   fill     = (int*)w;                   w += (size_t)NQn * 4;
    int*   sorted_s = (int*)w;                   w += (size_t)NEn * 4;         // 8 MB
    int*   bsum     = (int*)w;                   w += (size_t)SCAN_NB * 4;
    int*   bbase    = (int*)w;

    // CSR build
    zero_kernel   <<<256, 256, 0, stream>>>(cnt, NQn);
    hist_kernel   <<<2048, 256, 0, stream>>>(t, cnt);
    scan_bsum_kernel <<<SCAN_NB, 256, 0, stream>>>(cnt, bsum);
    scan_base_kernel <<<1, 64, 0, stream>>>(bsum, bbase, ptr);
    scan_final_kernel<<<SCAN_NB, 256, 0, stream>>>(cnt, bbase, ptr, fill);
    scatter_kernel<<<2048, 256, 0, stream>>>(t, s, fill, sorted_s);

    // projections + fused attention
    kvproj_kernel <<<1024, 256, 0, stream>>>(other, Wkv, kvb);
    node_kernel   <<<4096, 256, 0, stream>>>(input, Wq, ptr, sorted_s, kvb, Wo, bo, out);
}

// Round 5
// 1050.955 us; speedup vs baseline: 1.4909x; 1.4909x over previous
//
#include <hip/hip_runtime.h>
#include <hip/hip_bf16.h>
#include <math.h>

#define NQn 100000
#define NKVn 100000
#define NEn 2000000
// D=64, H=4, F=16. CSR scan: chunks of 1024.
#define SCAN_NB ((NQn + 1023) / 1024)

// ---------------- zero-init ------------------------------------------------
__global__ void zero_kernel(int* __restrict__ p, int n) {
    int i = blockIdx.x * blockDim.x + threadIdx.x;
    int stride = gridDim.x * blockDim.x;
    for (; i < n; i += stride) p[i] = 0;
}

// ---------------- CSR build: histogram ------------------------------------
__global__ void hist_kernel(const int* __restrict__ t, int* __restrict__ cnt) {
    int i = blockIdx.x * blockDim.x + threadIdx.x;
    int stride = gridDim.x * blockDim.x;
    for (; i < NEn; i += stride) atomicAdd(&cnt[t[i]], 1);
}

__global__ void scan_bsum_kernel(const int* __restrict__ cnt, int* __restrict__ bsum) {
    __shared__ int ls[256];
    int b = blockIdx.x;
    int base = b * 1024 + threadIdx.x * 4;
    int tot = 0;
    #pragma unroll
    for (int k = 0; k < 4; ++k) {
        int idx = base + k;
        tot += (idx < NQn) ? cnt[idx] : 0;
    }
    ls[threadIdx.x] = tot;
    __syncthreads();
    for (int off = 128; off > 0; off >>= 1) {
        if (threadIdx.x < off) ls[threadIdx.x] += ls[threadIdx.x + off];
        __syncthreads();
    }
    if (threadIdx.x == 0) bsum[b] = ls[0];
}

__global__ void scan_base_kernel(const int* __restrict__ bsum, int* __restrict__ bbase,
                                 int* __restrict__ ptr) {
    if (threadIdx.x == 0 && blockIdx.x == 0) {
        int run = 0;
        for (int b = 0; b < SCAN_NB; ++b) { bbase[b] = run; run += bsum[b]; }
        ptr[NQn] = run;   // == NEn
    }
}

__global__ void scan_final_kernel(const int* __restrict__ cnt, const int* __restrict__ bbase,
                                  int* __restrict__ ptr, int* __restrict__ fill) {
    __shared__ int ls[256];
    int b = blockIdx.x;
    int base = b * 1024 + threadIdx.x * 4;
    int c[4];
    int tot = 0;
    #pragma unroll
    for (int k = 0; k < 4; ++k) {
        int idx = base + k;
        c[k] = (idx < NQn) ? cnt[idx] : 0;
        tot += c[k];
    }
    ls[threadIdx.x] = tot;
    __syncthreads();
    for (int off = 1; off < 256; off <<= 1) {
        int v = (threadIdx.x >= off) ? ls[threadIdx.x - off] : 0;
        __syncthreads();
        ls[threadIdx.x] += v;
        __syncthreads();
    }
    int run = ((threadIdx.x > 0) ? ls[threadIdx.x - 1] : 0) + bbase[b];
    #pragma unroll
    for (int k = 0; k < 4; ++k) {
        int idx = base + k;
        if (idx < NQn) { ptr[idx] = run; fill[idx] = run; run += c[k]; }
    }
}

__global__ void scatter_kernel(const int* __restrict__ t, const int* __restrict__ s,
                               int* __restrict__ fill, int* __restrict__ sorted_s) {
    int i = blockIdx.x * blockDim.x + threadIdx.x;
    int stride = gridDim.x * blockDim.x;
    for (; i < NEn; i += stride) {
        int pos = atomicAdd(&fill[t[i]], 1);
        sorted_s[pos] = s[i];
    }
}

// ---------------- kv projection -> packed bf16 row [k(64) | v(64)] --------
__global__ void kvproj_kernel(const float* __restrict__ x, const float* __restrict__ W,
                              __hip_bfloat16* __restrict__ outh) {
    __shared__ float Wl[64 * 128];
    for (int i = threadIdx.x; i < 64 * 128; i += blockDim.x) Wl[i] = W[i];
    __syncthreads();
    const int lane = threadIdx.x & 63;
    const int wid  = blockIdx.x * (blockDim.x >> 6) + (threadIdx.x >> 6);
    const int nw   = gridDim.x * (blockDim.x >> 6);
    for (int r = wid; r < NKVn; r += nw) {
        float xv = x[(size_t)r * 64 + lane];
        float acc0 = 0.f, acc1 = 0.f;
        #pragma unroll
        for (int k = 0; k < 64; ++k) {
            float xk = __shfl(xv, k, 64);
            acc0 += xk * Wl[k * 128 + lane];        // k dim `lane`
            acc1 += xk * Wl[k * 128 + lane + 64];   // v dim `lane`
        }
        outh[(size_t)r * 128 + lane]      = __float2bfloat16(acc0);
        outh[(size_t)r * 128 + 64 + lane] = __float2bfloat16(acc1);
    }
}

// ---------------- fused node kernel ---------------------------------------
// wave per target node. kvh row = 64 uints (256B): lane l reads elements
// 2l,2l+1. Lanes 0-31: k pairs (head=lane>>3). Lanes 32-63: v pairs.
#define EDGE_STEP(u)                                                        \
    {                                                                       \
        float ea = __uint_as_float((u) << 16);                              \
        float eb = __uint_as_float((u) & 0xffff0000u);                      \
        float p = q0 * ea + q1 * eb;                                        \
        p += __shfl_xor(p, 4, 64);                                          \
        p += __shfl_xor(p, 2, 64);                                          \
        p += __shfl_xor(p, 1, 64);                                          \
        float ex = __expf(p * 0.25f);                                       \
        float exv = __shfl(ex, lane & 31, 64);                              \
        va0 += exv * ea;                                                    \
        va1 += exv * eb;                                                    \
        sl += ex;                                                           \
    }

__global__ void node_kernel(const float* __restrict__ input, const float* __restrict__ Wq,
                            const int* __restrict__ ptr, const int* __restrict__ sorted_s,
                            const unsigned* __restrict__ kvh,
                            const float* __restrict__ Wo, const float* __restrict__ bo,
                            float* __restrict__ out) {
    __shared__ float WqL[64 * 64];
    __shared__ float WoL[64 * 64];
    for (int i = threadIdx.x; i < 64 * 64; i += blockDim.x) {
        WqL[i] = Wq[i];
        WoL[i] = Wo[i];
    }
    __syncthreads();
    const int lane = threadIdx.x & 63;
    const int wid  = blockIdx.x * (blockDim.x >> 6) + (threadIdx.x >> 6);
    const int nw   = gridDim.x * (blockDim.x >> 6);
    const float b = bo[lane];

    for (int r = wid; r < NQn; r += nw) {
        // --- q projection into registers ---
        float xv = input[(size_t)r * 64 + lane];
        float qv = 0.f;
        #pragma unroll
        for (int k = 0; k < 64; ++k)
            qv += __shfl(xv, k, 64) * WqL[k * 64 + lane];
        // pack q pairs to match kvh lane layout (valid in lanes 0-31)
        float q0 = __shfl(qv, (2 * lane) & 63, 64);
        float q1 = __shfl(qv, (2 * lane + 1) & 63, 64);

        // --- edge loop (4-way unrolled for MLP) ---
        int beg = ptr[r], end = ptr[r + 1];
        float va0 = 0.f, va1 = 0.f, sl = 0.f;
        int e = beg;
        for (; e + 4 <= end; e += 4) {
            int s0 = sorted_s[e],     s1 = sorted_s[e + 1];
            int s2 = sorted_s[e + 2], s3 = sorted_s[e + 3];
            unsigned u0 = kvh[(size_t)s0 * 64 + lane];
            unsigned u1 = kvh[(size_t)s1 * 64 + lane];
            unsigned u2 = kvh[(size_t)s2 * 64 + lane];
            unsigned u3 = kvh[(size_t)s3 * 64 + lane];
            EDGE_STEP(u0); EDGE_STEP(u1); EDGE_STEP(u2); EDGE_STEP(u3);
        }
        for (; e < end; ++e) {
            int si = sorted_s[e];
            unsigned u = kvh[(size_t)si * 64 + lane];
            EDGE_STEP(u);
        }

        // --- normalize (v-lanes) ---
        float sg = __shfl(sl, (lane & 31) & 24, 64);   // head-group sum
        float v0n = (end > beg) ? va0 / sg : 0.f;
        float v1n = (end > beg) ? va1 / sg : 0.f;

        // --- output projection + bias ---
        float o = b;
        #pragma unroll
        for (int d2 = 0; d2 < 32; ++d2) {
            float w0 = __shfl(v0n, 32 + d2, 64);       // val[2*d2]
            float w1 = __shfl(v1n, 32 + d2, 64);       // val[2*d2+1]
            o += w0 * WoL[(2 * d2) * 64 + lane] + w1 * WoL[(2 * d2 + 1) * 64 + lane];
        }
        out[(size_t)r * 64 + lane] = o;
    }
}

extern "C" void kernel_launch(void* const* d_in, const int* in_sizes, int n_in,
                              void* d_out, int out_size, void* d_ws, size_t ws_size,
                              hipStream_t stream) {
    const float* input = (const float*)d_in[0];
    const float* other = (const float*)d_in[1];
    const int*   t     = (const int*)  d_in[2];
    const int*   s     = (const int*)  d_in[3];
    const float* Wq    = (const float*)d_in[4];
    const float* Wkv   = (const float*)d_in[5];
    const float* Wo    = (const float*)d_in[6];
    const float* bo    = (const float*)d_in[7];
    float* out = (float*)d_out;

    // workspace layout
    char* w = (char*)d_ws;
    __hip_bfloat16* kvh = (__hip_bfloat16*)w;    w += (size_t)NKVn * 128 * 2;  // 25.6 MB
    int*   cnt      = (int*)w;                   w += (size_t)NQn * 4;
    int*   ptr      = (int*)w;                   w += ((size_t)NQn + 1) * 4;
    int*   fill     = (int*)w;                   w += (size_t)NQn * 4;
    int*   sorted_s = (int*)w;                   w += (size_t)NEn * 4;         // 8 MB
    int*   bsum     = (int*)w;                   w += (size_t)SCAN_NB * 4;
    int*   bbase    = (int*)w;

    // CSR build
    zero_kernel      <<<256, 256, 0, stream>>>(cnt, NQn);
    hist_kernel      <<<2048, 256, 0, stream>>>(t, cnt);
    scan_bsum_kernel <<<SCAN_NB, 256, 0, stream>>>(cnt, bsum);
    scan_base_kernel <<<1, 64, 0, stream>>>(bsum, bbase, ptr);
    scan_final_kernel<<<SCAN_NB, 256, 0, stream>>>(cnt, bbase, ptr, fill);
    scatter_kernel   <<<2048, 256, 0, stream>>>(t, s, fill, sorted_s);

    // projections + fused attention
    kvproj_kernel<<<1024, 256, 0, stream>>>(other, Wkv, kvh);
    node_kernel  <<<4096, 256, 0, stream>>>(input, Wq, ptr, sorted_s,
                                            (const unsigned*)kvh, Wo, bo, out);
}